// Round 13
// baseline (218.849 us; speedup 1.0000x reference)
//
#include <hip/hip_runtime.h>
#include <hip/hip_fp16.h>

#define N_NODES 100000
#define N_EDGES 3200000
#define F_IN 16
#define HID 32

#define NPB 128                         // nodes per bin
#define NBIN 782                        // ceil(N_NODES / NPB)
#define NBLK_A 800                      // edge-pass blocks (r13: 512->800, LDS 62->44KB,
                                        //   3 blocks/CU; L2 merges the shorter runs)
#define EPB (N_EDGES / NBLK_A)          // 4000 edges per chunk (exact)
#define EPB2 (EPB / 2)                  // 2000 pair-loads per chunk (exact)
#define CAPB 4576                       // fixed per-bin region (mean 4092 + ~7.5 sigma)
#define CAPT 9                          // per-thread reg slots in gatherNode
#define SLOTS 4                         // per-thread pair slots in scatterC (2000/512)

typedef unsigned long long ull;
typedef float __attribute__((ext_vector_type(4))) f4v;
typedef float __attribute__((ext_vector_type(2))) f2v;

// ---- workspace layout (4-byte words) ----
#define OFF_GCA  0                      // NBIN ints (dst-bin cursors, DENSE — hot lines)
#define OFF_GCB  784                    // NBIN ints (src-bin cursors)
#define OFF_DIS  1568                   // N_NODES floats
#define OFF_XSH  101568                 // N*16 halfs = 800000 words
#define OFF_EB   901568                 // NBIN*CAPB uint2 (dst records; 8B records)
#define OFF_EBS  8058432                // NBIN*CAPB uint  (src records)
// total 11,636,864 words = 46.5 MB

__device__ inline float2 h2f(unsigned u)
{
    __half2 h = *reinterpret_cast<__half2*>(&u);
    return __half22float2(h);
}

// ---------------------------------------------------------------------------
// scatterC: single edge pass. LDS counting sort by coarse bin with a
// WAVE-SHFL scan; EARLY global reservation; DENSE counters (round-2 lesson;
// rounds 1/7: scattered global fp atomics at ANY scope cost ~32B HBM each).
// Round-12: eb/ebs stores are CACHED — L2 merges scattered writes, L3
// retains records for degK/gatherNode (+25us proven).
// Round-13: NBLK_A 800 (se[] 32KB, total LDS ~44KB -> 3 blocks/CU).
//   dst records eb[bin*CAPB + ...]: .x = src | dstlow<<17   .y = half(w)
//   src records ebs[bin*CAPB + ...]: srclow<<16 | half(w)
// ---------------------------------------------------------------------------
__global__ __launch_bounds__(512) void scatterC(
    const int* __restrict__ src, const int* __restrict__ dst,
    const float* __restrict__ w,
    int* __restrict__ gcurA, int* __restrict__ gcurB,
    uint2* __restrict__ eb, unsigned* __restrict__ ebs)
{
    __shared__ int cnt[1024];
    __shared__ int incl[1024];               // inclusive scan
    __shared__ int curs[1024];               // live cursors, then global bases
    __shared__ int wscr[8];
    __shared__ uint2 se[EPB];                // 32 KB staging (both phases)

    int t = threadIdx.x, blk = blockIdx.x;
    int base = blk * EPB;
    int lane = t & 63, wid = t >> 6;

    ull sreg[SLOTS], dreg[SLOTS], wreg[SLOTS];
#pragma unroll
    for (int i = 0; i < SLOTS; ++i) {
        int k = t + (i << 9);
        if (k < EPB2) {
            sreg[i] = __builtin_nontemporal_load((const ull*)(src + base) + k);
            dreg[i] = __builtin_nontemporal_load((const ull*)(dst + base) + k);
            wreg[i] = __builtin_nontemporal_load((const ull*)(w + base) + k);
        }
    }

    // ---------------- phase A: dst records ----------------
    cnt[2 * t] = 0; cnt[2 * t + 1] = 0;
    __syncthreads();
#pragma unroll
    for (int i = 0; i < SLOTS; ++i) {
        int k = t + (i << 9);
        if (k < EPB2) {
            atomicAdd(&cnt[(int)((unsigned)dreg[i] >> 7)], 1);
            atomicAdd(&cnt[(int)((unsigned)(dreg[i] >> 32) >> 7)], 1);
        }
    }
    __syncthreads();
    {
        int a0 = cnt[2 * t], a1 = cnt[2 * t + 1];
        int ps = a0 + a1;
        int v = ps;
#pragma unroll
        for (int off = 1; off < 64; off <<= 1) {
            int u = __shfl_up(v, off, 64);
            if (lane >= off) v += u;
        }
        if (lane == 63) wscr[wid] = v;
        __syncthreads();
        int wpre = 0;
#pragma unroll
        for (int j = 0; j < 8; ++j) wpre += (j < wid) ? wscr[j] : 0;
        int ebase = wpre + v - ps;
        incl[2 * t]     = ebase + a0;
        incl[2 * t + 1] = ebase + ps;
        curs[2 * t]     = ebase;
        curs[2 * t + 1] = ebase + a0;
    }
    __syncthreads();

    // EARLY reserve: issue global atomics now; results land in regs while the
    // place loop below runs (round-trip hidden under LDS work).
    int rbA0 = 0, rbA1 = 0;
    {
        int cA0 = cnt[t];
        if (cA0) rbA0 = atomicAdd(&gcurA[t], cA0);
        if (t + 512 < NBIN) {
            int cA1 = cnt[t + 512];
            if (cA1) rbA1 = atomicAdd(&gcurA[t + 512], cA1);
        }
    }

#pragma unroll
    for (int i = 0; i < SLOTS; ++i) {
        int k = t + (i << 9);
        if (k < EPB2) {
            int s0 = (int)((unsigned)sreg[i]), s1 = (int)((unsigned)(sreg[i] >> 32));
            int d0 = (int)((unsigned)dreg[i]), d1 = (int)((unsigned)(dreg[i] >> 32));
            unsigned h0 = (unsigned)__half_as_ushort(
                              __float2half_rn(__uint_as_float((unsigned)wreg[i])));
            unsigned h1 = (unsigned)__half_as_ushort(
                              __float2half_rn(__uint_as_float((unsigned)(wreg[i] >> 32))));
            int p0 = atomicAdd(&curs[d0 >> 7], 1);
            se[p0] = make_uint2((unsigned)s0 | ((unsigned)(d0 & 127) << 17),
                                ((unsigned)(d0 >> 7) << 16) | h0);
            int p1 = atomicAdd(&curs[d1 >> 7], 1);
            se[p1] = make_uint2((unsigned)s1 | ((unsigned)(d1 & 127) << 17),
                                ((unsigned)(d1 >> 7) << 16) | h1);
        }
    }
    __syncthreads();
    // publish global bases (curs free: cursor values == incl values now)
    curs[t] = rbA0;
    if (t + 512 < NBIN) curs[t + 512] = rbA1;
    __syncthreads();
    for (int p = t; p < EPB; p += 512) {
        uint2 v = se[p];
        int bin = (int)(v.y >> 16);
        int local = p - (incl[bin] - cnt[bin]);
        int pos = curs[bin] + local;
        if (pos < CAPB) {
            ull pv = ((ull)(v.y & 0xFFFFu) << 32) | (ull)v.x;
            *((ull*)(eb + (size_t)bin * CAPB) + pos) = pv;   // CACHED store
        }
    }
    __syncthreads();

    // ---------------- phase B: src records ----------------
    cnt[2 * t] = 0; cnt[2 * t + 1] = 0;
    __syncthreads();
#pragma unroll
    for (int i = 0; i < SLOTS; ++i) {
        int k = t + (i << 9);
        if (k < EPB2) {
            atomicAdd(&cnt[(int)((unsigned)sreg[i] >> 7)], 1);
            atomicAdd(&cnt[(int)((unsigned)(sreg[i] >> 32) >> 7)], 1);
        }
    }
    __syncthreads();
    {
        int a0 = cnt[2 * t], a1 = cnt[2 * t + 1];
        int ps = a0 + a1;
        int v = ps;
#pragma unroll
        for (int off = 1; off < 64; off <<= 1) {
            int u = __shfl_up(v, off, 64);
            if (lane >= off) v += u;
        }
        if (lane == 63) wscr[wid] = v;
        __syncthreads();
        int wpre = 0;
#pragma unroll
        for (int j = 0; j < 8; ++j) wpre += (j < wid) ? wscr[j] : 0;
        int ebase = wpre + v - ps;
        incl[2 * t]     = ebase + a0;
        incl[2 * t + 1] = ebase + ps;
        curs[2 * t]     = ebase;
        curs[2 * t + 1] = ebase + a0;
    }
    __syncthreads();

    // EARLY reserve for phase B
    int rbB0 = 0, rbB1 = 0;
    {
        int cB0 = cnt[t];
        if (cB0) rbB0 = atomicAdd(&gcurB[t], cB0);
        if (t + 512 < NBIN) {
            int cB1 = cnt[t + 512];
            if (cB1) rbB1 = atomicAdd(&gcurB[t + 512], cB1);
        }
    }

#pragma unroll
    for (int i = 0; i < SLOTS; ++i) {
        int k = t + (i << 9);
        if (k < EPB2) {
            int s0 = (int)((unsigned)sreg[i]), s1 = (int)((unsigned)(sreg[i] >> 32));
            unsigned h0 = (unsigned)__half_as_ushort(
                              __float2half_rn(__uint_as_float((unsigned)wreg[i])));
            unsigned h1 = (unsigned)__half_as_ushort(
                              __float2half_rn(__uint_as_float((unsigned)(wreg[i] >> 32))));
            int p0 = atomicAdd(&curs[s0 >> 7], 1);
            se[p0] = make_uint2((unsigned)s0, h0);      // .x = full src id (bin = x>>7)
            int p1 = atomicAdd(&curs[s1 >> 7], 1);
            se[p1] = make_uint2((unsigned)s1, h1);
        }
    }
    __syncthreads();
    curs[t] = rbB0;
    if (t + 512 < NBIN) curs[t + 512] = rbB1;
    __syncthreads();
    for (int p = t; p < EPB; p += 512) {
        uint2 v = se[p];
        int bin = (int)(v.x >> 7);
        int local = p - (incl[bin] - cnt[bin]);
        int pos = curs[bin] + local;
        if (pos < CAPB) {
            unsigned rec = ((v.x & 127u) << 16) | v.y;
            ebs[(size_t)bin * CAPB + pos] = rec;        // CACHED store
        }
    }
}

// ---------------------------------------------------------------------------
// degK: per-bucket deg reduction in LDS (8-way wave-replicated accumulators)
// -> dis, then write fp16 scaled rows xs[n] = dis[n]*x[n] (stays warm).
// Round-13: ebs read as uint2 pairs (half the load instructions).
// ---------------------------------------------------------------------------
__global__ __launch_bounds__(512) void degK(
    const unsigned* __restrict__ ebs, const int* __restrict__ gcurB,
    const float* __restrict__ x, float* __restrict__ dis,
    __half* __restrict__ xsh)
{
    __shared__ float sdeg[8][NPB];
    int b = blockIdx.x, t = threadIdx.x;
    int wid = t >> 6;
    for (int i = t; i < 8 * NPB; i += 512) ((float*)sdeg)[i] = 0.f;
    __syncthreads();
    int m = gcurB[b];
    if (m > CAPB) m = CAPB;
    const unsigned* seg = ebs + (size_t)b * CAPB;
    int m2 = m >> 1;
    for (int j = t; j < m2; j += 512) {
        uint2 v = ((const uint2*)seg)[j];
        float w0 = __half2float(__ushort_as_half((unsigned short)(v.x & 0xFFFF)));
        float w1 = __half2float(__ushort_as_half((unsigned short)(v.y & 0xFFFF)));
        atomicAdd(&sdeg[wid][v.x >> 16], w0);
        atomicAdd(&sdeg[wid][v.y >> 16], w1);
    }
    if (t == 0 && (m & 1)) {
        unsigned v = seg[m - 1];
        atomicAdd(&sdeg[0][v >> 16],
                  __half2float(__ushort_as_half((unsigned short)(v & 0xFFFF))));
    }
    __syncthreads();
    int n0 = b * NPB;
    if (t < NPB) {
        float dg = ((sdeg[0][t] + sdeg[1][t]) + (sdeg[2][t] + sdeg[3][t]))
                 + ((sdeg[4][t] + sdeg[5][t]) + (sdeg[6][t] + sdeg[7][t]));
        float ds = (dg > 0.f) ? rsqrtf(fmaxf(dg, 1e-12f)) : 0.f;
        sdeg[0][t] = ds;
        if (n0 + t < N_NODES) dis[n0 + t] = ds;
    }
    __syncthreads();
    for (int i = t; i < NPB * 8; i += 512) {
        int node = n0 + (i >> 3);
        if (node < N_NODES) {
            float ds = sdeg[0][i >> 3];
            f2v xv = __builtin_nontemporal_load(((const f2v*)x) + node * 8 + (i & 7));
            ((__half2*)xsh)[node * 8 + (i & 7)] =
                __float22half2_rn(make_float2(xv.x * ds, xv.y * ds));
        }
    }
}

// ---------------------------------------------------------------------------
// gatherNode: B_dst + node epilogue. LDS ~38.6 KB -> 4 blocks/CU (32 waves).
// Walk: 2-way edge-parity x 2-way feature-split, unroll 8 (round-9; MLP=8).
// Epilogue: 128-thread per-node form (round-11 lesson: the 512-thread
// variant spilled xv/tv to scratch — VGPR 128, 115 MB spill traffic).
// (H == 0 in the reference; R is dead since it only multiplies H.)
// ---------------------------------------------------------------------------
__global__ __launch_bounds__(512) void gatherNode(
    const uint2* __restrict__ eb, const int* __restrict__ gcurA,
    const float* __restrict__ dis, const __half* __restrict__ xsh,
    const float* __restrict__ x,
    const float* __restrict__ W_xz, const float* __restrict__ b_xz,
    const float* __restrict__ b_hz,
    const float* __restrict__ W_xh, const float* __restrict__ b_xh,
    const float* __restrict__ b_hh,
    const float* __restrict__ W_lin, const float* __restrict__ b_lin,
    float* __restrict__ out)
{
    __shared__ unsigned       sl[CAPB];       // 18304 B: record lo (src|dstlow<<17)
    __shared__ unsigned short sw[CAPB];       //  9152 B: record half(w)
    __shared__ int   cnt[NPB], scn[NPB], cur[NPB];
    __shared__ int   wtot;
    __shared__ float stx[NPB * 17];
    __shared__ float sbz[HID], sbh[HID], sWl[HID];
    __shared__ float sdis[NPB];

    float* sWz = (float*)sl;                  // weights overlay sl after walk
    float* sWh = (float*)sl + 2 * F_IN * HID; // (8 KB <= 18304 B)

    int t = threadIdx.x, b = blockIdx.x;
    int lane = t & 63, wid = t >> 6;
    int m = gcurA[b];
    if (m > CAPB) m = CAPB;
    const uint2* seg = eb + (size_t)b * CAPB;

    // phase 0: stage edges in registers (single nt pass over eb; L3-hot)
    ull r[CAPT];
#pragma unroll
    for (int i = 0; i < CAPT; ++i) {
        int k = t + (i << 9);
        if (k < m) r[i] = __builtin_nontemporal_load((const ull*)(seg + k));
    }

    if (t < NPB) cnt[t] = 0;
    if (t < HID) {
        sbz[t] = b_xz[t] + b_hz[t];
        sbh[t] = b_xh[t] + b_hh[t];
        sWl[t] = W_lin[t];
    }
    if (t < NPB) {
        int n = b * NPB + t;
        sdis[t] = (n < N_NODES) ? dis[n] : 0.f;
    }
    __syncthreads();

    // phase 1: sort by exact dst (hist -> shfl scan -> place)
#pragma unroll
    for (int i = 0; i < CAPT; ++i) {
        int k = t + (i << 9);
        if (k < m) atomicAdd(&cnt[(unsigned)r[i] >> 17], 1);
    }
    __syncthreads();
    {
        int v = (t < NPB) ? cnt[t] : 0;
#pragma unroll
        for (int off = 1; off < 64; off <<= 1) {
            int u = __shfl_up(v, off, 64);
            if (lane >= off) v += u;
        }
        if (t == 63) wtot = v;                // wave-0 total (t 0..63)
        __syncthreads();
        if (t < NPB) {
            int vv = v + ((wid == 1) ? wtot : 0);
            scn[t] = vv;
            cur[t] = vv - cnt[t];
        }
    }
    __syncthreads();
#pragma unroll
    for (int i = 0; i < CAPT; ++i) {
        int k = t + (i << 9);
        if (k < m) {
            unsigned lo = (unsigned)r[i], hi = (unsigned)(r[i] >> 32);
            int p = atomicAdd(&cur[lo >> 17], 1);
            sl[p] = lo;
            sw[p] = (unsigned short)hi;
        }
    }
    __syncthreads();

    // phase 2: parity x feature-half walk, unroll 8 (8 outstanding uint4)
    {
        int nloc = t >> 2;
        int h    = t & 3;
        int par  = h >> 1;
        int hf   = h & 1;
        int r1 = scn[nloc];
        int r0 = r1 - cnt[nloc];
        float dn = sdis[nloc];
        float a0 = 0.f, a1 = 0.f, a2 = 0.f, a3 = 0.f;
        float a4 = 0.f, a5 = 0.f, a6 = 0.f, a7 = 0.f;
        int j = r0 + par;
        for (; j + 14 < r1; j += 16) {
            unsigned e[8]; unsigned short wv[8]; uint4 p[8];
#pragma unroll
            for (int q = 0; q < 8; ++q) { e[q] = sl[j + 2 * q]; wv[q] = sw[j + 2 * q]; }
#pragma unroll
            for (int q = 0; q < 8; ++q)
                p[q] = *(const uint4*)(xsh + ((size_t)(e[q] & 0x1FFFF) << 4) + (hf << 3));
#pragma unroll
            for (int q = 0; q < 8; ++q) {
                float lw = -__half2float(__ushort_as_half(wv[q])) * dn;
                float2 f0 = h2f(p[q].x), f1 = h2f(p[q].y);
                float2 f2 = h2f(p[q].z), f3 = h2f(p[q].w);
                a0 = fmaf(lw, f0.x, a0); a1 = fmaf(lw, f0.y, a1);
                a2 = fmaf(lw, f1.x, a2); a3 = fmaf(lw, f1.y, a3);
                a4 = fmaf(lw, f2.x, a4); a5 = fmaf(lw, f2.y, a5);
                a6 = fmaf(lw, f3.x, a6); a7 = fmaf(lw, f3.y, a7);
            }
        }
        for (; j < r1; j += 2) {
            unsigned e0 = sl[j];
            float lw = -__half2float(__ushort_as_half(sw[j])) * dn;
            uint4 p0 = *(const uint4*)(xsh + ((size_t)(e0 & 0x1FFFF) << 4) + (hf << 3));
            float2 f0 = h2f(p0.x), f1 = h2f(p0.y);
            float2 f2 = h2f(p0.z), f3 = h2f(p0.w);
            a0 = fmaf(lw, f0.x, a0); a1 = fmaf(lw, f0.y, a1);
            a2 = fmaf(lw, f1.x, a2); a3 = fmaf(lw, f1.y, a3);
            a4 = fmaf(lw, f2.x, a4); a5 = fmaf(lw, f2.y, a5);
            a6 = fmaf(lw, f3.x, a6); a7 = fmaf(lw, f3.y, a7);
        }
        // combine parity partners (lanes differ in bit 1 of t: h=0<->2, 1<->3)
        a0 += __shfl_xor(a0, 2, 64); a1 += __shfl_xor(a1, 2, 64);
        a2 += __shfl_xor(a2, 2, 64); a3 += __shfl_xor(a3, 2, 64);
        a4 += __shfl_xor(a4, 2, 64); a5 += __shfl_xor(a5, 2, 64);
        a6 += __shfl_xor(a6, 2, 64); a7 += __shfl_xor(a7, 2, 64);
        // lane writes its quarter: features (hf<<3) + (par<<2) + [0..4)
        float w0 = par ? a4 : a0;
        float w1 = par ? a5 : a1;
        float w2 = par ? a6 : a2;
        float w3 = par ? a7 : a3;
        float* tp = &stx[nloc * 17 + (hf << 3) + (par << 2)];
        tp[0] = w0; tp[1] = w1; tp[2] = w2; tp[3] = w3;
    }
    __syncthreads();

    // phase 2b: weights overlay into the (now free) sl region
    for (int i = t; i < 2 * F_IN * HID; i += 512) { sWz[i] = W_xz[i]; sWh[i] = W_xh[i]; }
    __syncthreads();

    // phase 3: epilogue (128 threads/node-block; round-11 lesson: keep arrays
    // in the low-pressure phase only)
    int n = b * NPB + t;
    if (t >= NPB || n >= N_NODES) return;

    float xv[F_IN], tv[F_IN];
    const f4v* xr = (const f4v*)(x + (size_t)n * F_IN);
#pragma unroll
    for (int q = 0; q < 4; ++q) {
        f4v a = __builtin_nontemporal_load(xr + q);
        xv[4 * q + 0] = a.x; xv[4 * q + 1] = a.y; xv[4 * q + 2] = a.z; xv[4 * q + 3] = a.w;
    }
#pragma unroll
    for (int k = 0; k < F_IN; ++k) tv[k] = stx[t * 17 + k];

    float acc = 0.f;
    for (int j = 0; j < HID; ++j) {
        float zp = sbz[j];
        float hp = sbh[j];
#pragma unroll
        for (int k = 0; k < F_IN; ++k) {
            zp = fmaf(xv[k], sWz[k * HID + j], zp);
            zp = fmaf(tv[k], sWz[F_IN * HID + k * HID + j], zp);
            hp = fmaf(xv[k], sWh[k * HID + j], hp);
            hp = fmaf(tv[k], sWh[F_IN * HID + k * HID + j], hp);
        }
        float z  = 1.f / (1.f + __expf(-zp));
        float ht = tanhf(hp);
        float hn = (1.f - z) * ht;
        acc = fmaf(fmaxf(hn, 0.f), sWl[j], acc);
    }
    out[n] = acc + b_lin[0];
}

// ---------------------------------------------------------------------------
extern "C" void kernel_launch(void* const* d_in, const int* in_sizes, int n_in,
                              void* d_out, int out_size, void* d_ws, size_t ws_size,
                              hipStream_t stream)
{
    const float* x     = (const float*)d_in[0];
    const int*   ei    = (const int*)d_in[1];   // [2, E] delivered as int32
    const float* ew    = (const float*)d_in[2];
    const float* W_xz  = (const float*)d_in[3];
    const float* b_xz  = (const float*)d_in[4];
    const float* b_hz  = (const float*)d_in[6];
    const float* W_xh  = (const float*)d_in[11];
    const float* b_xh  = (const float*)d_in[12];
    const float* b_hh  = (const float*)d_in[14];
    const float* W_lin = (const float*)d_in[15];
    const float* b_lin = (const float*)d_in[16];
    float*       out   = (float*)d_out;

    int*      wsi = (int*)d_ws;
    float*    wsf = (float*)d_ws;

    int*      gcurA = wsi + OFF_GCA;
    int*      gcurB = wsi + OFF_GCB;
    float*    dis   = wsf + OFF_DIS;
    __half*   xsh   = (__half*)(wsi + OFF_XSH);
    uint2*    eb    = (uint2*)(wsi + OFF_EB);
    unsigned* ebs   = (unsigned*)(wsi + OFF_EBS);

    const int* src = ei;
    const int* dst = ei + N_EDGES;

    hipMemsetAsync(d_ws, 0, (size_t)OFF_DIS * 4, stream);   // zero gcurA/gcurB
    scatterC<<<NBLK_A, 512, 0, stream>>>(src, dst, ew, gcurA, gcurB, eb, ebs);
    degK<<<NBIN, 512, 0, stream>>>(ebs, gcurB, x, dis, xsh);
    gatherNode<<<NBIN, 512, 0, stream>>>(eb, gcurA, dis, xsh, x,
        W_xz, b_xz, b_hz, W_xh, b_xh, b_hh, W_lin, b_lin, out);
}

// Round 14
// 204.583 us; speedup vs baseline: 1.0697x; 1.0697x over previous
//
#include <hip/hip_runtime.h>
#include <hip/hip_fp16.h>

#define N_NODES 100000
#define N_EDGES 3200000
#define F_IN 16
#define HID 32

#define NPB 128                         // nodes per bin
#define NBIN 782                        // ceil(N_NODES / NPB)
#define NBLK_A 512                      // edge-pass blocks (r13 lesson: 800 shrank
                                        //   per-(bin,block) runs to 41B < sector ->
                                        //   write amplification; 512 = 64B runs)
#define EPB (N_EDGES / NBLK_A)          // 6250 edges per chunk (exact)
#define EPB2 (EPB / 2)                  // 3125 pair-loads per chunk (exact)
#define CAPB 4576                       // fixed per-bin region (mean 4092 + ~7.5 sigma)
#define CAPT 9                          // per-thread reg slots in gatherNode
#define SLOTS 7                         // per-thread pair slots in scatterC

typedef unsigned long long ull;
typedef float __attribute__((ext_vector_type(4))) f4v;
typedef float __attribute__((ext_vector_type(2))) f2v;

// ---- workspace layout (4-byte words) ----
#define OFF_GCA  0                      // NBIN ints (dst-bin cursors, DENSE — hot lines)
#define OFF_GCB  784                    // NBIN ints (src-bin cursors)
#define OFF_DIS  1568                   // N_NODES floats
#define OFF_XSH  101568                 // N*16 halfs = 800000 words
#define OFF_EB   901568                 // NBIN*CAPB uint2 (dst records; 8B records)
#define OFF_EBS  8058432                // NBIN*CAPB uint  (src records)
// total 11,636,864 words = 46.5 MB

__device__ inline float2 h2f(unsigned u)
{
    __half2 h = *reinterpret_cast<__half2*>(&u);
    return __half22float2(h);
}

// ---------------------------------------------------------------------------
// scatterC: single edge pass. LDS counting sort by coarse bin with a
// WAVE-SHFL scan; EARLY global reservation; DENSE counters (round-2 lesson;
// rounds 1/7: scattered global fp atomics at ANY scope cost ~32B HBM each).
// Round-12 (+25us proven): eb/ebs stores are CACHED — L2 merges scattered
// writes, L3 retains records for degK/gatherNode.
//   dst records eb[bin*CAPB + ...]: .x = src | dstlow<<17   .y = half(w)
//   src records ebs[bin*CAPB + ...]: srclow<<16 | half(w)
// ---------------------------------------------------------------------------
__global__ __launch_bounds__(512) void scatterC(
    const int* __restrict__ src, const int* __restrict__ dst,
    const float* __restrict__ w,
    int* __restrict__ gcurA, int* __restrict__ gcurB,
    uint2* __restrict__ eb, unsigned* __restrict__ ebs)
{
    __shared__ int cnt[1024];
    __shared__ int incl[1024];               // inclusive scan
    __shared__ int curs[1024];               // live cursors, then global bases
    __shared__ int wscr[8];
    __shared__ uint2 se[EPB];                // 50 KB staging (both phases)

    int t = threadIdx.x, blk = blockIdx.x;
    int base = blk * EPB;
    int lane = t & 63, wid = t >> 6;

    ull sreg[SLOTS], dreg[SLOTS], wreg[SLOTS];
#pragma unroll
    for (int i = 0; i < SLOTS; ++i) {
        int k = t + (i << 9);
        if (k < EPB2) {
            sreg[i] = __builtin_nontemporal_load((const ull*)(src + base) + k);
            dreg[i] = __builtin_nontemporal_load((const ull*)(dst + base) + k);
            wreg[i] = __builtin_nontemporal_load((const ull*)(w + base) + k);
        }
    }

    // ---------------- phase A: dst records ----------------
    cnt[2 * t] = 0; cnt[2 * t + 1] = 0;
    __syncthreads();
#pragma unroll
    for (int i = 0; i < SLOTS; ++i) {
        int k = t + (i << 9);
        if (k < EPB2) {
            atomicAdd(&cnt[(int)((unsigned)dreg[i] >> 7)], 1);
            atomicAdd(&cnt[(int)((unsigned)(dreg[i] >> 32) >> 7)], 1);
        }
    }
    __syncthreads();
    {
        int a0 = cnt[2 * t], a1 = cnt[2 * t + 1];
        int ps = a0 + a1;
        int v = ps;
#pragma unroll
        for (int off = 1; off < 64; off <<= 1) {
            int u = __shfl_up(v, off, 64);
            if (lane >= off) v += u;
        }
        if (lane == 63) wscr[wid] = v;
        __syncthreads();
        int wpre = 0;
#pragma unroll
        for (int j = 0; j < 8; ++j) wpre += (j < wid) ? wscr[j] : 0;
        int ebase = wpre + v - ps;
        incl[2 * t]     = ebase + a0;
        incl[2 * t + 1] = ebase + ps;
        curs[2 * t]     = ebase;
        curs[2 * t + 1] = ebase + a0;
    }
    __syncthreads();

    // EARLY reserve: issue global atomics now; results land in regs while the
    // place loop below runs (round-trip hidden under LDS work).
    int rbA0 = 0, rbA1 = 0;
    {
        int cA0 = cnt[t];
        if (cA0) rbA0 = atomicAdd(&gcurA[t], cA0);
        if (t + 512 < NBIN) {
            int cA1 = cnt[t + 512];
            if (cA1) rbA1 = atomicAdd(&gcurA[t + 512], cA1);
        }
    }

#pragma unroll
    for (int i = 0; i < SLOTS; ++i) {
        int k = t + (i << 9);
        if (k < EPB2) {
            int s0 = (int)((unsigned)sreg[i]), s1 = (int)((unsigned)(sreg[i] >> 32));
            int d0 = (int)((unsigned)dreg[i]), d1 = (int)((unsigned)(dreg[i] >> 32));
            unsigned h0 = (unsigned)__half_as_ushort(
                              __float2half_rn(__uint_as_float((unsigned)wreg[i])));
            unsigned h1 = (unsigned)__half_as_ushort(
                              __float2half_rn(__uint_as_float((unsigned)(wreg[i] >> 32))));
            int p0 = atomicAdd(&curs[d0 >> 7], 1);
            se[p0] = make_uint2((unsigned)s0 | ((unsigned)(d0 & 127) << 17),
                                ((unsigned)(d0 >> 7) << 16) | h0);
            int p1 = atomicAdd(&curs[d1 >> 7], 1);
            se[p1] = make_uint2((unsigned)s1 | ((unsigned)(d1 & 127) << 17),
                                ((unsigned)(d1 >> 7) << 16) | h1);
        }
    }
    __syncthreads();
    // publish global bases (curs free: cursor values == incl values now)
    curs[t] = rbA0;
    if (t + 512 < NBIN) curs[t + 512] = rbA1;
    __syncthreads();
    for (int p = t; p < EPB; p += 512) {
        uint2 v = se[p];
        int bin = (int)(v.y >> 16);
        int local = p - (incl[bin] - cnt[bin]);
        int pos = curs[bin] + local;
        if (pos < CAPB) {
            ull pv = ((ull)(v.y & 0xFFFFu) << 32) | (ull)v.x;
            *((ull*)(eb + (size_t)bin * CAPB) + pos) = pv;   // CACHED store
        }
    }
    __syncthreads();

    // ---------------- phase B: src records ----------------
    cnt[2 * t] = 0; cnt[2 * t + 1] = 0;
    __syncthreads();
#pragma unroll
    for (int i = 0; i < SLOTS; ++i) {
        int k = t + (i << 9);
        if (k < EPB2) {
            atomicAdd(&cnt[(int)((unsigned)sreg[i] >> 7)], 1);
            atomicAdd(&cnt[(int)((unsigned)(sreg[i] >> 32) >> 7)], 1);
        }
    }
    __syncthreads();
    {
        int a0 = cnt[2 * t], a1 = cnt[2 * t + 1];
        int ps = a0 + a1;
        int v = ps;
#pragma unroll
        for (int off = 1; off < 64; off <<= 1) {
            int u = __shfl_up(v, off, 64);
            if (lane >= off) v += u;
        }
        if (lane == 63) wscr[wid] = v;
        __syncthreads();
        int wpre = 0;
#pragma unroll
        for (int j = 0; j < 8; ++j) wpre += (j < wid) ? wscr[j] : 0;
        int ebase = wpre + v - ps;
        incl[2 * t]     = ebase + a0;
        incl[2 * t + 1] = ebase + ps;
        curs[2 * t]     = ebase;
        curs[2 * t + 1] = ebase + a0;
    }
    __syncthreads();

    // EARLY reserve for phase B
    int rbB0 = 0, rbB1 = 0;
    {
        int cB0 = cnt[t];
        if (cB0) rbB0 = atomicAdd(&gcurB[t], cB0);
        if (t + 512 < NBIN) {
            int cB1 = cnt[t + 512];
            if (cB1) rbB1 = atomicAdd(&gcurB[t + 512], cB1);
        }
    }

#pragma unroll
    for (int i = 0; i < SLOTS; ++i) {
        int k = t + (i << 9);
        if (k < EPB2) {
            int s0 = (int)((unsigned)sreg[i]), s1 = (int)((unsigned)(sreg[i] >> 32));
            unsigned h0 = (unsigned)__half_as_ushort(
                              __float2half_rn(__uint_as_float((unsigned)wreg[i])));
            unsigned h1 = (unsigned)__half_as_ushort(
                              __float2half_rn(__uint_as_float((unsigned)(wreg[i] >> 32))));
            int p0 = atomicAdd(&curs[s0 >> 7], 1);
            se[p0] = make_uint2((unsigned)s0, h0);      // .x = full src id (bin = x>>7)
            int p1 = atomicAdd(&curs[s1 >> 7], 1);
            se[p1] = make_uint2((unsigned)s1, h1);
        }
    }
    __syncthreads();
    curs[t] = rbB0;
    if (t + 512 < NBIN) curs[t + 512] = rbB1;
    __syncthreads();
    for (int p = t; p < EPB; p += 512) {
        uint2 v = se[p];
        int bin = (int)(v.x >> 7);
        int local = p - (incl[bin] - cnt[bin]);
        int pos = curs[bin] + local;
        if (pos < CAPB) {
            unsigned rec = ((v.x & 127u) << 16) | v.y;
            ebs[(size_t)bin * CAPB + pos] = rec;        // CACHED store
        }
    }
}

// ---------------------------------------------------------------------------
// degK: per-bucket deg reduction in LDS (8-way wave-replicated accumulators)
// -> dis, then write fp16 scaled rows xs[n] = dis[n]*x[n] (stays warm).
// ebs read as uint2 pairs (half the load instructions).
// ---------------------------------------------------------------------------
__global__ __launch_bounds__(512) void degK(
    const unsigned* __restrict__ ebs, const int* __restrict__ gcurB,
    const float* __restrict__ x, float* __restrict__ dis,
    __half* __restrict__ xsh)
{
    __shared__ float sdeg[8][NPB];
    int b = blockIdx.x, t = threadIdx.x;
    int wid = t >> 6;
    for (int i = t; i < 8 * NPB; i += 512) ((float*)sdeg)[i] = 0.f;
    __syncthreads();
    int m = gcurB[b];
    if (m > CAPB) m = CAPB;
    const unsigned* seg = ebs + (size_t)b * CAPB;
    int m2 = m >> 1;
    for (int j = t; j < m2; j += 512) {
        uint2 v = ((const uint2*)seg)[j];
        float w0 = __half2float(__ushort_as_half((unsigned short)(v.x & 0xFFFF)));
        float w1 = __half2float(__ushort_as_half((unsigned short)(v.y & 0xFFFF)));
        atomicAdd(&sdeg[wid][v.x >> 16], w0);
        atomicAdd(&sdeg[wid][v.y >> 16], w1);
    }
    if (t == 0 && (m & 1)) {
        unsigned v = seg[m - 1];
        atomicAdd(&sdeg[0][v >> 16],
                  __half2float(__ushort_as_half((unsigned short)(v & 0xFFFF))));
    }
    __syncthreads();
    int n0 = b * NPB;
    if (t < NPB) {
        float dg = ((sdeg[0][t] + sdeg[1][t]) + (sdeg[2][t] + sdeg[3][t]))
                 + ((sdeg[4][t] + sdeg[5][t]) + (sdeg[6][t] + sdeg[7][t]));
        float ds = (dg > 0.f) ? rsqrtf(fmaxf(dg, 1e-12f)) : 0.f;
        sdeg[0][t] = ds;
        if (n0 + t < N_NODES) dis[n0 + t] = ds;
    }
    __syncthreads();
    for (int i = t; i < NPB * 8; i += 512) {
        int node = n0 + (i >> 3);
        if (node < N_NODES) {
            float ds = sdeg[0][i >> 3];
            f2v xv = ((const f2v*)x)[node * 8 + (i & 7)];
            ((__half2*)xsh)[node * 8 + (i & 7)] =
                __float22half2_rn(make_float2(xv.x * ds, xv.y * ds));
        }
    }
}

// ---------------------------------------------------------------------------
// gatherNode: B_dst + node epilogue. LDS ~38.6 KB -> 4 blocks/CU (32 waves).
// Walk: 2-way edge-parity x 2-way feature-split, unroll 8 (round-9; MLP=8).
// Epilogue: 128-thread per-node form (round-11 lesson: the 512-thread
// variant spilled xv/tv to scratch); x loads CACHED (L3-hot from degK).
// (H == 0 in the reference; R is dead since it only multiplies H.)
// ---------------------------------------------------------------------------
__global__ __launch_bounds__(512) void gatherNode(
    const uint2* __restrict__ eb, const int* __restrict__ gcurA,
    const float* __restrict__ dis, const __half* __restrict__ xsh,
    const float* __restrict__ x,
    const float* __restrict__ W_xz, const float* __restrict__ b_xz,
    const float* __restrict__ b_hz,
    const float* __restrict__ W_xh, const float* __restrict__ b_xh,
    const float* __restrict__ b_hh,
    const float* __restrict__ W_lin, const float* __restrict__ b_lin,
    float* __restrict__ out)
{
    __shared__ unsigned       sl[CAPB];       // 18304 B: record lo (src|dstlow<<17)
    __shared__ unsigned short sw[CAPB];       //  9152 B: record half(w)
    __shared__ int   cnt[NPB], scn[NPB], cur[NPB];
    __shared__ int   wtot;
    __shared__ float stx[NPB * 17];
    __shared__ float sbz[HID], sbh[HID], sWl[HID];
    __shared__ float sdis[NPB];

    float* sWz = (float*)sl;                  // weights overlay sl after walk
    float* sWh = (float*)sl + 2 * F_IN * HID; // (8 KB <= 18304 B)

    int t = threadIdx.x, b = blockIdx.x;
    int lane = t & 63, wid = t >> 6;
    int m = gcurA[b];
    if (m > CAPB) m = CAPB;
    const uint2* seg = eb + (size_t)b * CAPB;

    // phase 0: stage edges in registers (single nt pass over eb; L3-hot)
    ull r[CAPT];
#pragma unroll
    for (int i = 0; i < CAPT; ++i) {
        int k = t + (i << 9);
        if (k < m) r[i] = __builtin_nontemporal_load((const ull*)(seg + k));
    }

    if (t < NPB) cnt[t] = 0;
    if (t < HID) {
        sbz[t] = b_xz[t] + b_hz[t];
        sbh[t] = b_xh[t] + b_hh[t];
        sWl[t] = W_lin[t];
    }
    if (t < NPB) {
        int n = b * NPB + t;
        sdis[t] = (n < N_NODES) ? dis[n] : 0.f;
    }
    __syncthreads();

    // phase 1: sort by exact dst (hist -> shfl scan -> place)
#pragma unroll
    for (int i = 0; i < CAPT; ++i) {
        int k = t + (i << 9);
        if (k < m) atomicAdd(&cnt[(unsigned)r[i] >> 17], 1);
    }
    __syncthreads();
    {
        int v = (t < NPB) ? cnt[t] : 0;
#pragma unroll
        for (int off = 1; off < 64; off <<= 1) {
            int u = __shfl_up(v, off, 64);
            if (lane >= off) v += u;
        }
        if (t == 63) wtot = v;                // wave-0 total (t 0..63)
        __syncthreads();
        if (t < NPB) {
            int vv = v + ((wid == 1) ? wtot : 0);
            scn[t] = vv;
            cur[t] = vv - cnt[t];
        }
    }
    __syncthreads();
#pragma unroll
    for (int i = 0; i < CAPT; ++i) {
        int k = t + (i << 9);
        if (k < m) {
            unsigned lo = (unsigned)r[i], hi = (unsigned)(r[i] >> 32);
            int p = atomicAdd(&cur[lo >> 17], 1);
            sl[p] = lo;
            sw[p] = (unsigned short)hi;
        }
    }
    __syncthreads();

    // phase 2: parity x feature-half walk, unroll 8 (8 outstanding uint4)
    {
        int nloc = t >> 2;
        int h    = t & 3;
        int par  = h >> 1;
        int hf   = h & 1;
        int r1 = scn[nloc];
        int r0 = r1 - cnt[nloc];
        float dn = sdis[nloc];
        float a0 = 0.f, a1 = 0.f, a2 = 0.f, a3 = 0.f;
        float a4 = 0.f, a5 = 0.f, a6 = 0.f, a7 = 0.f;
        int j = r0 + par;
        for (; j + 14 < r1; j += 16) {
            unsigned e[8]; unsigned short wv[8]; uint4 p[8];
#pragma unroll
            for (int q = 0; q < 8; ++q) { e[q] = sl[j + 2 * q]; wv[q] = sw[j + 2 * q]; }
#pragma unroll
            for (int q = 0; q < 8; ++q)
                p[q] = *(const uint4*)(xsh + ((size_t)(e[q] & 0x1FFFF) << 4) + (hf << 3));
#pragma unroll
            for (int q = 0; q < 8; ++q) {
                float lw = -__half2float(__ushort_as_half(wv[q])) * dn;
                float2 f0 = h2f(p[q].x), f1 = h2f(p[q].y);
                float2 f2 = h2f(p[q].z), f3 = h2f(p[q].w);
                a0 = fmaf(lw, f0.x, a0); a1 = fmaf(lw, f0.y, a1);
                a2 = fmaf(lw, f1.x, a2); a3 = fmaf(lw, f1.y, a3);
                a4 = fmaf(lw, f2.x, a4); a5 = fmaf(lw, f2.y, a5);
                a6 = fmaf(lw, f3.x, a6); a7 = fmaf(lw, f3.y, a7);
            }
        }
        for (; j < r1; j += 2) {
            unsigned e0 = sl[j];
            float lw = -__half2float(__ushort_as_half(sw[j])) * dn;
            uint4 p0 = *(const uint4*)(xsh + ((size_t)(e0 & 0x1FFFF) << 4) + (hf << 3));
            float2 f0 = h2f(p0.x), f1 = h2f(p0.y);
            float2 f2 = h2f(p0.z), f3 = h2f(p0.w);
            a0 = fmaf(lw, f0.x, a0); a1 = fmaf(lw, f0.y, a1);
            a2 = fmaf(lw, f1.x, a2); a3 = fmaf(lw, f1.y, a3);
            a4 = fmaf(lw, f2.x, a4); a5 = fmaf(lw, f2.y, a5);
            a6 = fmaf(lw, f3.x, a6); a7 = fmaf(lw, f3.y, a7);
        }
        // combine parity partners (lanes differ in bit 1 of t: h=0<->2, 1<->3)
        a0 += __shfl_xor(a0, 2, 64); a1 += __shfl_xor(a1, 2, 64);
        a2 += __shfl_xor(a2, 2, 64); a3 += __shfl_xor(a3, 2, 64);
        a4 += __shfl_xor(a4, 2, 64); a5 += __shfl_xor(a5, 2, 64);
        a6 += __shfl_xor(a6, 2, 64); a7 += __shfl_xor(a7, 2, 64);
        // lane writes its quarter: features (hf<<3) + (par<<2) + [0..4)
        float w0 = par ? a4 : a0;
        float w1 = par ? a5 : a1;
        float w2 = par ? a6 : a2;
        float w3 = par ? a7 : a3;
        float* tp = &stx[nloc * 17 + (hf << 3) + (par << 2)];
        tp[0] = w0; tp[1] = w1; tp[2] = w2; tp[3] = w3;
    }
    __syncthreads();

    // phase 2b: weights overlay into the (now free) sl region
    for (int i = t; i < 2 * F_IN * HID; i += 512) { sWz[i] = W_xz[i]; sWh[i] = W_xh[i]; }
    __syncthreads();

    // phase 3: epilogue (128 threads/node-block; round-11 lesson: keep arrays
    // in the low-pressure phase only)
    int n = b * NPB + t;
    if (t >= NPB || n >= N_NODES) return;

    float xv[F_IN], tv[F_IN];
    const f4v* xr = (const f4v*)(x + (size_t)n * F_IN);
#pragma unroll
    for (int q = 0; q < 4; ++q) {
        f4v a = xr[q];                        // cached: x is L3-hot from degK
        xv[4 * q + 0] = a.x; xv[4 * q + 1] = a.y; xv[4 * q + 2] = a.z; xv[4 * q + 3] = a.w;
    }
#pragma unroll
    for (int k = 0; k < F_IN; ++k) tv[k] = stx[t * 17 + k];

    float acc = 0.f;
    for (int j = 0; j < HID; ++j) {
        float zp = sbz[j];
        float hp = sbh[j];
#pragma unroll
        for (int k = 0; k < F_IN; ++k) {
            zp = fmaf(xv[k], sWz[k * HID + j], zp);
            zp = fmaf(tv[k], sWz[F_IN * HID + k * HID + j], zp);
            hp = fmaf(xv[k], sWh[k * HID + j], hp);
            hp = fmaf(tv[k], sWh[F_IN * HID + k * HID + j], hp);
        }
        float z  = 1.f / (1.f + __expf(-zp));
        float ht = tanhf(hp);
        float hn = (1.f - z) * ht;
        acc = fmaf(fmaxf(hn, 0.f), sWl[j], acc);
    }
    out[n] = acc + b_lin[0];
}

// ---------------------------------------------------------------------------
extern "C" void kernel_launch(void* const* d_in, const int* in_sizes, int n_in,
                              void* d_out, int out_size, void* d_ws, size_t ws_size,
                              hipStream_t stream)
{
    const float* x     = (const float*)d_in[0];
    const int*   ei    = (const int*)d_in[1];   // [2, E] delivered as int32
    const float* ew    = (const float*)d_in[2];
    const float* W_xz  = (const float*)d_in[3];
    const float* b_xz  = (const float*)d_in[4];
    const float* b_hz  = (const float*)d_in[6];
    const float* W_xh  = (const float*)d_in[11];
    const float* b_xh  = (const float*)d_in[12];
    const float* b_hh  = (const float*)d_in[14];
    const float* W_lin = (const float*)d_in[15];
    const float* b_lin = (const float*)d_in[16];
    float*       out   = (float*)d_out;

    int*      wsi = (int*)d_ws;
    float*    wsf = (float*)d_ws;

    int*      gcurA = wsi + OFF_GCA;
    int*      gcurB = wsi + OFF_GCB;
    float*    dis   = wsf + OFF_DIS;
    __half*   xsh   = (__half*)(wsi + OFF_XSH);
    uint2*    eb    = (uint2*)(wsi + OFF_EB);
    unsigned* ebs   = (unsigned*)(wsi + OFF_EBS);

    const int* src = ei;
    const int* dst = ei + N_EDGES;

    hipMemsetAsync(d_ws, 0, (size_t)OFF_DIS * 4, stream);   // zero gcurA/gcurB
    scatterC<<<NBLK_A, 512, 0, stream>>>(src, dst, ew, gcurA, gcurB, eb, ebs);
    degK<<<NBIN, 512, 0, stream>>>(ebs, gcurB, x, dis, xsh);
    gatherNode<<<NBIN, 512, 0, stream>>>(eb, gcurA, dis, xsh, x,
        W_xz, b_xz, b_hz, W_xh, b_xh, b_hh, W_lin, b_lin, out);
}

// Round 15
// 200.175 us; speedup vs baseline: 1.0933x; 1.0220x over previous
//
#include <hip/hip_runtime.h>
#include <hip/hip_fp16.h>

#define N_NODES 100000
#define N_EDGES 3200000
#define F_IN 16
#define HID 32

#define NPB 128                         // nodes per bin
#define NBIN 782                        // ceil(N_NODES / NPB)
#define NBLK_A 512                      // edge-pass blocks (r13 lesson: 8-record=64B runs)
#define EPB (N_EDGES / NBLK_A)          // 6250 edges per chunk (exact)
#define EPB2 (EPB / 2)                  // 3125 pair-loads per chunk (exact)
#define CAPB 4576                       // fixed per-bin region (mean 4092 + ~7.5 sigma)
#define CAPT 9                          // per-thread reg slots in gatherNode
#define SLOTS 7                         // per-thread pair slots in scatterC

typedef unsigned long long ull;
typedef float __attribute__((ext_vector_type(4))) f4v;
typedef float __attribute__((ext_vector_type(2))) f2v;

// ---- workspace layout (4-byte words) ----
#define OFF_GCA  0                      // NBIN ints (dst-bin cursors, DENSE — hot lines)
#define OFF_GCB  784                    // NBIN ints (src-bin cursors)
#define OFF_DIS  1568                   // N_NODES floats
#define OFF_XSH  101568                 // N*16 halfs = 800000 words
#define OFF_EB   901568                 // NBIN*CAPB uint2 (dst records; 8B records)
#define OFF_EBS  8058432                // NBIN*CAPB uint  (src records)
// total 11,636,864 words = 46.5 MB

__device__ inline float2 h2f(unsigned u)
{
    __half2 h = *reinterpret_cast<__half2*>(&u);
    return __half22float2(h);
}

// ---------------------------------------------------------------------------
// scatterC: single edge pass. LDS counting sort by coarse bin with a
// WAVE-SHFL scan; EARLY global reservation; DENSE counters (round-2 lesson;
// rounds 1/7: scattered global fp atomics at ANY scope cost ~32B HBM each).
// Round-12 (+25us proven): eb/ebs stores CACHED. Round-15: fp16 weight
// conversions hoisted (computed once, used in both phases; VGPR headroom is
// free — occupancy is LDS-bound at 2 blocks/CU).
//   dst records eb[bin*CAPB + ...]: .x = src | dstlow<<17   .y = half(w)
//   src records ebs[bin*CAPB + ...]: srclow<<16 | half(w)
// ---------------------------------------------------------------------------
__global__ __launch_bounds__(512) void scatterC(
    const int* __restrict__ src, const int* __restrict__ dst,
    const float* __restrict__ w,
    int* __restrict__ gcurA, int* __restrict__ gcurB,
    uint2* __restrict__ eb, unsigned* __restrict__ ebs)
{
    __shared__ int cnt[1024];
    __shared__ int incl[1024];               // inclusive scan
    __shared__ int curs[1024];               // live cursors, then global bases
    __shared__ int wscr[8];
    __shared__ uint2 se[EPB];                // 50 KB staging (both phases)

    int t = threadIdx.x, blk = blockIdx.x;
    int base = blk * EPB;
    int lane = t & 63, wid = t >> 6;

    ull sreg[SLOTS], dreg[SLOTS];
    unsigned hreg0[SLOTS], hreg1[SLOTS];     // hoisted fp16(w) for both phases
#pragma unroll
    for (int i = 0; i < SLOTS; ++i) {
        int k = t + (i << 9);
        if (k < EPB2) {
            sreg[i] = __builtin_nontemporal_load((const ull*)(src + base) + k);
            dreg[i] = __builtin_nontemporal_load((const ull*)(dst + base) + k);
            ull wr  = __builtin_nontemporal_load((const ull*)(w + base) + k);
            hreg0[i] = (unsigned)__half_as_ushort(
                           __float2half_rn(__uint_as_float((unsigned)wr)));
            hreg1[i] = (unsigned)__half_as_ushort(
                           __float2half_rn(__uint_as_float((unsigned)(wr >> 32))));
        }
    }

    // ---------------- phase A: dst records ----------------
    cnt[2 * t] = 0; cnt[2 * t + 1] = 0;
    __syncthreads();
#pragma unroll
    for (int i = 0; i < SLOTS; ++i) {
        int k = t + (i << 9);
        if (k < EPB2) {
            atomicAdd(&cnt[(int)((unsigned)dreg[i] >> 7)], 1);
            atomicAdd(&cnt[(int)((unsigned)(dreg[i] >> 32) >> 7)], 1);
        }
    }
    __syncthreads();
    {
        int a0 = cnt[2 * t], a1 = cnt[2 * t + 1];
        int ps = a0 + a1;
        int v = ps;
#pragma unroll
        for (int off = 1; off < 64; off <<= 1) {
            int u = __shfl_up(v, off, 64);
            if (lane >= off) v += u;
        }
        if (lane == 63) wscr[wid] = v;
        __syncthreads();
        int wpre = 0;
#pragma unroll
        for (int j = 0; j < 8; ++j) wpre += (j < wid) ? wscr[j] : 0;
        int ebase = wpre + v - ps;
        incl[2 * t]     = ebase + a0;
        incl[2 * t + 1] = ebase + ps;
        curs[2 * t]     = ebase;
        curs[2 * t + 1] = ebase + a0;
    }
    __syncthreads();

    // EARLY reserve: issue global atomics now; results land in regs while the
    // place loop below runs (round-trip hidden under LDS work).
    int rbA0 = 0, rbA1 = 0;
    {
        int cA0 = cnt[t];
        if (cA0) rbA0 = atomicAdd(&gcurA[t], cA0);
        if (t + 512 < NBIN) {
            int cA1 = cnt[t + 512];
            if (cA1) rbA1 = atomicAdd(&gcurA[t + 512], cA1);
        }
    }

#pragma unroll
    for (int i = 0; i < SLOTS; ++i) {
        int k = t + (i << 9);
        if (k < EPB2) {
            int s0 = (int)((unsigned)sreg[i]), s1 = (int)((unsigned)(sreg[i] >> 32));
            int d0 = (int)((unsigned)dreg[i]), d1 = (int)((unsigned)(dreg[i] >> 32));
            int p0 = atomicAdd(&curs[d0 >> 7], 1);
            se[p0] = make_uint2((unsigned)s0 | ((unsigned)(d0 & 127) << 17),
                                ((unsigned)(d0 >> 7) << 16) | hreg0[i]);
            int p1 = atomicAdd(&curs[d1 >> 7], 1);
            se[p1] = make_uint2((unsigned)s1 | ((unsigned)(d1 & 127) << 17),
                                ((unsigned)(d1 >> 7) << 16) | hreg1[i]);
        }
    }
    __syncthreads();
    // publish global bases (curs free: cursor values == incl values now)
    curs[t] = rbA0;
    if (t + 512 < NBIN) curs[t + 512] = rbA1;
    __syncthreads();
    for (int p = t; p < EPB; p += 512) {
        uint2 v = se[p];
        int bin = (int)(v.y >> 16);
        int local = p - (incl[bin] - cnt[bin]);
        int pos = curs[bin] + local;
        if (pos < CAPB) {
            ull pv = ((ull)(v.y & 0xFFFFu) << 32) | (ull)v.x;
            *((ull*)(eb + (size_t)bin * CAPB) + pos) = pv;   // CACHED store
        }
    }
    __syncthreads();

    // ---------------- phase B: src records ----------------
    cnt[2 * t] = 0; cnt[2 * t + 1] = 0;
    __syncthreads();
#pragma unroll
    for (int i = 0; i < SLOTS; ++i) {
        int k = t + (i << 9);
        if (k < EPB2) {
            atomicAdd(&cnt[(int)((unsigned)sreg[i] >> 7)], 1);
            atomicAdd(&cnt[(int)((unsigned)(sreg[i] >> 32) >> 7)], 1);
        }
    }
    __syncthreads();
    {
        int a0 = cnt[2 * t], a1 = cnt[2 * t + 1];
        int ps = a0 + a1;
        int v = ps;
#pragma unroll
        for (int off = 1; off < 64; off <<= 1) {
            int u = __shfl_up(v, off, 64);
            if (lane >= off) v += u;
        }
        if (lane == 63) wscr[wid] = v;
        __syncthreads();
        int wpre = 0;
#pragma unroll
        for (int j = 0; j < 8; ++j) wpre += (j < wid) ? wscr[j] : 0;
        int ebase = wpre + v - ps;
        incl[2 * t]     = ebase + a0;
        incl[2 * t + 1] = ebase + ps;
        curs[2 * t]     = ebase;
        curs[2 * t + 1] = ebase + a0;
    }
    __syncthreads();

    // EARLY reserve for phase B
    int rbB0 = 0, rbB1 = 0;
    {
        int cB0 = cnt[t];
        if (cB0) rbB0 = atomicAdd(&gcurB[t], cB0);
        if (t + 512 < NBIN) {
            int cB1 = cnt[t + 512];
            if (cB1) rbB1 = atomicAdd(&gcurB[t + 512], cB1);
        }
    }

#pragma unroll
    for (int i = 0; i < SLOTS; ++i) {
        int k = t + (i << 9);
        if (k < EPB2) {
            int s0 = (int)((unsigned)sreg[i]), s1 = (int)((unsigned)(sreg[i] >> 32));
            int p0 = atomicAdd(&curs[s0 >> 7], 1);
            se[p0] = make_uint2((unsigned)s0, hreg0[i]); // .x = full src id (bin = x>>7)
            int p1 = atomicAdd(&curs[s1 >> 7], 1);
            se[p1] = make_uint2((unsigned)s1, hreg1[i]);
        }
    }
    __syncthreads();
    curs[t] = rbB0;
    if (t + 512 < NBIN) curs[t + 512] = rbB1;
    __syncthreads();
    for (int p = t; p < EPB; p += 512) {
        uint2 v = se[p];
        int bin = (int)(v.x >> 7);
        int local = p - (incl[bin] - cnt[bin]);
        int pos = curs[bin] + local;
        if (pos < CAPB) {
            unsigned rec = ((v.x & 127u) << 16) | v.y;
            ebs[(size_t)bin * CAPB + pos] = rec;        // CACHED store
        }
    }
}

// ---------------------------------------------------------------------------
// degK: per-bucket deg reduction in LDS (8-way wave-replicated accumulators)
// -> dis, then write fp16 scaled rows xs[n] = dis[n]*x[n] (stays warm).
// ebs read as uint2 pairs (half the load instructions).
// ---------------------------------------------------------------------------
__global__ __launch_bounds__(512) void degK(
    const unsigned* __restrict__ ebs, const int* __restrict__ gcurB,
    const float* __restrict__ x, float* __restrict__ dis,
    __half* __restrict__ xsh)
{
    __shared__ float sdeg[8][NPB];
    int b = blockIdx.x, t = threadIdx.x;
    int wid = t >> 6;
    for (int i = t; i < 8 * NPB; i += 512) ((float*)sdeg)[i] = 0.f;
    __syncthreads();
    int m = gcurB[b];
    if (m > CAPB) m = CAPB;
    const unsigned* seg = ebs + (size_t)b * CAPB;
    int m2 = m >> 1;
    for (int j = t; j < m2; j += 512) {
        uint2 v = ((const uint2*)seg)[j];
        float w0 = __half2float(__ushort_as_half((unsigned short)(v.x & 0xFFFF)));
        float w1 = __half2float(__ushort_as_half((unsigned short)(v.y & 0xFFFF)));
        atomicAdd(&sdeg[wid][v.x >> 16], w0);
        atomicAdd(&sdeg[wid][v.y >> 16], w1);
    }
    if (t == 0 && (m & 1)) {
        unsigned v = seg[m - 1];
        atomicAdd(&sdeg[0][v >> 16],
                  __half2float(__ushort_as_half((unsigned short)(v & 0xFFFF))));
    }
    __syncthreads();
    int n0 = b * NPB;
    if (t < NPB) {
        float dg = ((sdeg[0][t] + sdeg[1][t]) + (sdeg[2][t] + sdeg[3][t]))
                 + ((sdeg[4][t] + sdeg[5][t]) + (sdeg[6][t] + sdeg[7][t]));
        float ds = (dg > 0.f) ? rsqrtf(fmaxf(dg, 1e-12f)) : 0.f;
        sdeg[0][t] = ds;
        if (n0 + t < N_NODES) dis[n0 + t] = ds;
    }
    __syncthreads();
    for (int i = t; i < NPB * 8; i += 512) {
        int node = n0 + (i >> 3);
        if (node < N_NODES) {
            float ds = sdeg[0][i >> 3];
            f2v xv = ((const f2v*)x)[node * 8 + (i & 7)];
            ((__half2*)xsh)[node * 8 + (i & 7)] =
                __float22half2_rn(make_float2(xv.x * ds, xv.y * ds));
        }
    }
}

// ---------------------------------------------------------------------------
// gatherNode: B_dst + node epilogue. LDS ~38.6 KB -> 4 blocks/CU (32 waves).
// Walk: 2-way edge-parity x 2-way feature-split, unroll 8 (round-9; MLP=8).
// Epilogue: 128-thread per-node form (round-11 lesson: 512-thread spilled);
// round-15: fast tanh via __expf (branch-free, correct saturation) replaces
// libm tanhf in the 32-iteration serial loop.
// (H == 0 in the reference; R is dead since it only multiplies H.)
// ---------------------------------------------------------------------------
__global__ __launch_bounds__(512) void gatherNode(
    const uint2* __restrict__ eb, const int* __restrict__ gcurA,
    const float* __restrict__ dis, const __half* __restrict__ xsh,
    const float* __restrict__ x,
    const float* __restrict__ W_xz, const float* __restrict__ b_xz,
    const float* __restrict__ b_hz,
    const float* __restrict__ W_xh, const float* __restrict__ b_xh,
    const float* __restrict__ b_hh,
    const float* __restrict__ W_lin, const float* __restrict__ b_lin,
    float* __restrict__ out)
{
    __shared__ unsigned       sl[CAPB];       // 18304 B: record lo (src|dstlow<<17)
    __shared__ unsigned short sw[CAPB];       //  9152 B: record half(w)
    __shared__ int   cnt[NPB], scn[NPB], cur[NPB];
    __shared__ int   wtot;
    __shared__ float stx[NPB * 17];
    __shared__ float sbz[HID], sbh[HID], sWl[HID];
    __shared__ float sdis[NPB];

    float* sWz = (float*)sl;                  // weights overlay sl after walk
    float* sWh = (float*)sl + 2 * F_IN * HID; // (8 KB <= 18304 B)

    int t = threadIdx.x, b = blockIdx.x;
    int lane = t & 63, wid = t >> 6;
    int m = gcurA[b];
    if (m > CAPB) m = CAPB;
    const uint2* seg = eb + (size_t)b * CAPB;

    // phase 0: stage edges in registers (single nt pass over eb; L3-hot)
    ull r[CAPT];
#pragma unroll
    for (int i = 0; i < CAPT; ++i) {
        int k = t + (i << 9);
        if (k < m) r[i] = __builtin_nontemporal_load((const ull*)(seg + k));
    }

    if (t < NPB) cnt[t] = 0;
    if (t < HID) {
        sbz[t] = b_xz[t] + b_hz[t];
        sbh[t] = b_xh[t] + b_hh[t];
        sWl[t] = W_lin[t];
    }
    if (t < NPB) {
        int n = b * NPB + t;
        sdis[t] = (n < N_NODES) ? dis[n] : 0.f;
    }
    __syncthreads();

    // phase 1: sort by exact dst (hist -> shfl scan -> place)
#pragma unroll
    for (int i = 0; i < CAPT; ++i) {
        int k = t + (i << 9);
        if (k < m) atomicAdd(&cnt[(unsigned)r[i] >> 17], 1);
    }
    __syncthreads();
    {
        int v = (t < NPB) ? cnt[t] : 0;
#pragma unroll
        for (int off = 1; off < 64; off <<= 1) {
            int u = __shfl_up(v, off, 64);
            if (lane >= off) v += u;
        }
        if (t == 63) wtot = v;                // wave-0 total (t 0..63)
        __syncthreads();
        if (t < NPB) {
            int vv = v + ((wid == 1) ? wtot : 0);
            scn[t] = vv;
            cur[t] = vv - cnt[t];
        }
    }
    __syncthreads();
#pragma unroll
    for (int i = 0; i < CAPT; ++i) {
        int k = t + (i << 9);
        if (k < m) {
            unsigned lo = (unsigned)r[i], hi = (unsigned)(r[i] >> 32);
            int p = atomicAdd(&cur[lo >> 17], 1);
            sl[p] = lo;
            sw[p] = (unsigned short)hi;
        }
    }
    __syncthreads();

    // phase 2: parity x feature-half walk, unroll 8 (8 outstanding uint4)
    {
        int nloc = t >> 2;
        int h    = t & 3;
        int par  = h >> 1;
        int hf   = h & 1;
        int r1 = scn[nloc];
        int r0 = r1 - cnt[nloc];
        float dn = sdis[nloc];
        float a0 = 0.f, a1 = 0.f, a2 = 0.f, a3 = 0.f;
        float a4 = 0.f, a5 = 0.f, a6 = 0.f, a7 = 0.f;
        int j = r0 + par;
        for (; j + 14 < r1; j += 16) {
            unsigned e[8]; unsigned short wv[8]; uint4 p[8];
#pragma unroll
            for (int q = 0; q < 8; ++q) { e[q] = sl[j + 2 * q]; wv[q] = sw[j + 2 * q]; }
#pragma unroll
            for (int q = 0; q < 8; ++q)
                p[q] = *(const uint4*)(xsh + ((size_t)(e[q] & 0x1FFFF) << 4) + (hf << 3));
#pragma unroll
            for (int q = 0; q < 8; ++q) {
                float lw = -__half2float(__ushort_as_half(wv[q])) * dn;
                float2 f0 = h2f(p[q].x), f1 = h2f(p[q].y);
                float2 f2 = h2f(p[q].z), f3 = h2f(p[q].w);
                a0 = fmaf(lw, f0.x, a0); a1 = fmaf(lw, f0.y, a1);
                a2 = fmaf(lw, f1.x, a2); a3 = fmaf(lw, f1.y, a3);
                a4 = fmaf(lw, f2.x, a4); a5 = fmaf(lw, f2.y, a5);
                a6 = fmaf(lw, f3.x, a6); a7 = fmaf(lw, f3.y, a7);
            }
        }
        for (; j < r1; j += 2) {
            unsigned e0 = sl[j];
            float lw = -__half2float(__ushort_as_half(sw[j])) * dn;
            uint4 p0 = *(const uint4*)(xsh + ((size_t)(e0 & 0x1FFFF) << 4) + (hf << 3));
            float2 f0 = h2f(p0.x), f1 = h2f(p0.y);
            float2 f2 = h2f(p0.z), f3 = h2f(p0.w);
            a0 = fmaf(lw, f0.x, a0); a1 = fmaf(lw, f0.y, a1);
            a2 = fmaf(lw, f1.x, a2); a3 = fmaf(lw, f1.y, a3);
            a4 = fmaf(lw, f2.x, a4); a5 = fmaf(lw, f2.y, a5);
            a6 = fmaf(lw, f3.x, a6); a7 = fmaf(lw, f3.y, a7);
        }
        // combine parity partners (lanes differ in bit 1 of t: h=0<->2, 1<->3)
        a0 += __shfl_xor(a0, 2, 64); a1 += __shfl_xor(a1, 2, 64);
        a2 += __shfl_xor(a2, 2, 64); a3 += __shfl_xor(a3, 2, 64);
        a4 += __shfl_xor(a4, 2, 64); a5 += __shfl_xor(a5, 2, 64);
        a6 += __shfl_xor(a6, 2, 64); a7 += __shfl_xor(a7, 2, 64);
        // lane writes its quarter: features (hf<<3) + (par<<2) + [0..4)
        float w0 = par ? a4 : a0;
        float w1 = par ? a5 : a1;
        float w2 = par ? a6 : a2;
        float w3 = par ? a7 : a3;
        float* tp = &stx[nloc * 17 + (hf << 3) + (par << 2)];
        tp[0] = w0; tp[1] = w1; tp[2] = w2; tp[3] = w3;
    }
    __syncthreads();

    // phase 2b: weights overlay into the (now free) sl region
    for (int i = t; i < 2 * F_IN * HID; i += 512) { sWz[i] = W_xz[i]; sWh[i] = W_xh[i]; }
    __syncthreads();

    // phase 3: epilogue (128 threads/node-block; round-11 lesson: keep arrays
    // in the low-pressure phase only)
    int n = b * NPB + t;
    if (t >= NPB || n >= N_NODES) return;

    float xv[F_IN], tv[F_IN];
    const f4v* xr = (const f4v*)(x + (size_t)n * F_IN);
#pragma unroll
    for (int q = 0; q < 4; ++q) {
        f4v a = xr[q];                        // cached: x is L3-hot from degK
        xv[4 * q + 0] = a.x; xv[4 * q + 1] = a.y; xv[4 * q + 2] = a.z; xv[4 * q + 3] = a.w;
    }
#pragma unroll
    for (int k = 0; k < F_IN; ++k) tv[k] = stx[t * 17 + k];

    float acc = 0.f;
    for (int j = 0; j < HID; ++j) {
        float zp = sbz[j];
        float hp = sbh[j];
#pragma unroll
        for (int k = 0; k < F_IN; ++k) {
            zp = fmaf(xv[k], sWz[k * HID + j], zp);
            zp = fmaf(tv[k], sWz[F_IN * HID + k * HID + j], zp);
            hp = fmaf(xv[k], sWh[k * HID + j], hp);
            hp = fmaf(tv[k], sWh[F_IN * HID + k * HID + j], hp);
        }
        float z  = 1.f / (1.f + __expf(-zp));
        // fast tanh: 1 - 2/(e^{2h}+1); exp overflow/underflow saturate correctly
        float eh = __expf(2.f * hp);
        float ht = 1.f - 2.f / (eh + 1.f);
        float hn = (1.f - z) * ht;
        acc = fmaf(fmaxf(hn, 0.f), sWl[j], acc);
    }
    out[n] = acc + b_lin[0];
}

// ---------------------------------------------------------------------------
extern "C" void kernel_launch(void* const* d_in, const int* in_sizes, int n_in,
                              void* d_out, int out_size, void* d_ws, size_t ws_size,
                              hipStream_t stream)
{
    const float* x     = (const float*)d_in[0];
    const int*   ei    = (const int*)d_in[1];   // [2, E] delivered as int32
    const float* ew    = (const float*)d_in[2];
    const float* W_xz  = (const float*)d_in[3];
    const float* b_xz  = (const float*)d_in[4];
    const float* b_hz  = (const float*)d_in[6];
    const float* W_xh  = (const float*)d_in[11];
    const float* b_xh  = (const float*)d_in[12];
    const float* b_hh  = (const float*)d_in[14];
    const float* W_lin = (const float*)d_in[15];
    const float* b_lin = (const float*)d_in[16];
    float*       out   = (float*)d_out;

    int*      wsi = (int*)d_ws;
    float*    wsf = (float*)d_ws;

    int*      gcurA = wsi + OFF_GCA;
    int*      gcurB = wsi + OFF_GCB;
    float*    dis   = wsf + OFF_DIS;
    __half*   xsh   = (__half*)(wsi + OFF_XSH);
    uint2*    eb    = (uint2*)(wsi + OFF_EB);
    unsigned* ebs   = (unsigned*)(wsi + OFF_EBS);

    const int* src = ei;
    const int* dst = ei + N_EDGES;

    hipMemsetAsync(d_ws, 0, (size_t)OFF_DIS * 4, stream);   // zero gcurA/gcurB
    scatterC<<<NBLK_A, 512, 0, stream>>>(src, dst, ew, gcurA, gcurB, eb, ebs);
    degK<<<NBIN, 512, 0, stream>>>(ebs, gcurB, x, dis, xsh);
    gatherNode<<<NBIN, 512, 0, stream>>>(eb, gcurA, dis, xsh, x,
        W_xz, b_xz, b_hz, W_xh, b_xh, b_hh, W_lin, b_lin, out);
}